// Round 9
// baseline (69.409 us; speedup 1.0000x reference)
//
#include <hip/hip_runtime.h>

// PHOG: lap = dw3x3(x, laplacian); gx,gy = dw3x3(lap, sobel); mag/ang -> 9-bin
// hist over pyramid cells (1+4+16), L1-ish then L2 normalize.
//
// R9 = R8 structure (8wx8t thread tiles, wave == one 64x64 cell, no LDS,
// rolling-3 rows) with the binning rewritten in inline asm using the VOP3
// CLAMP output modifier: p_i = clamp(C'*|gy| - S'*fx) with 1e35-prescaled
// constants saturates to exact 0/1 -- deletes all 9 v_med3 per pixel, and
// |gy| folds as a free abs input modifier. 22 asm insts/px vs 32 before.
// Boundary sin-consts live in SGPRs (one SGPR read per VALU inst). Lap rows
// 1..8 skip the row-mask multiply (specialized variant).

#define H_IMG 256
#define W_IMG 256

// boundary constants prescaled by 1e35: S'=sin(b)*1e35, C'=cos(b)*1e35
#define BS0 1.7364817766693033e34f
#define BC0 9.84807753012208e34f
#define BS1 5.0e34f
#define BC1 8.660254037844387e34f
#define BS2 7.66044443118978e34f
#define BC2 6.427876096865393e34f
#define BS3 9.396926207859084e34f
#define BC3 3.420201433256687e34f

// one x row: 12 floats = window cols gc0-2..gc0+9; OOB cols masked to 0
__device__ __forceinline__ void load_xrow12(const float* __restrict__ xim, int gr, bool valid,
                                            int o0, int o5, int gc0, float mlo, float mhi,
                                            float r[12]) {
  if (valid) {
    const float* p = xim + gr * W_IMG;
    float2 a = *reinterpret_cast<const float2*>(p + o0);
    float2 b = *reinterpret_cast<const float2*>(p + gc0);
    float2 c = *reinterpret_cast<const float2*>(p + gc0 + 2);
    float2 d = *reinterpret_cast<const float2*>(p + gc0 + 4);
    float2 e = *reinterpret_cast<const float2*>(p + gc0 + 6);
    float2 f = *reinterpret_cast<const float2*>(p + o5);
    r[0] = a.x * mlo; r[1] = a.y * mlo;
    r[2] = b.x;  r[3] = b.y;  r[4] = c.x;  r[5] = c.y;
    r[6] = d.x;  r[7] = d.y;  r[8] = e.x;  r[9] = e.y;
    r[10] = f.x * mhi; r[11] = f.y * mhi;
  } else {
#pragma unroll
    for (int i = 0; i < 12; ++i) r[i] = 0.f;
  }
}

// interior lap row (no row mask)
__device__ __forceinline__ void lap_row10(float dst[10], const float u[12], const float m[12],
                                          const float d[12], float wm0, float wm9) {
#pragma unroll
  for (int j = 0; j < 10; ++j)
    dst[j] = (u[j + 1] + d[j + 1]) + fmaf(-4.f, m[j + 1], m[j] + m[j + 2]);
  dst[0] *= wm0;
  dst[9] *= wm9;
}

// edge lap row (first/last: row mask may be 0)
__device__ __forceinline__ void lap_row10_rm(float dst[10], const float u[12], const float m[12],
                                             const float d[12], float wm0, float wm9, float rowm) {
#pragma unroll
  for (int j = 0; j < 10; ++j) {
    float v = (u[j + 1] + d[j + 1]) + fmaf(-4.f, m[j + 1], m[j] + m[j + 2]);
    dst[j] = v * rowm;
  }
  dst[0] *= wm0;
  dst[9] *= wm9;
}

// 9-boundary cumulative binning, one pixel. p_i = clamp(C'*|gy| - S'*fx) in
// {0,1} (1e35 prescale saturates); acc[i] += mag*p_i. 22 VALU insts, no med3.
__device__ __forceinline__ void bin9(float fx, float gy, float mag, float acc[10]) {
  const float s0 = BS0, s1 = BS1, s2 = BS2, s3 = BS3;
  const float c0 = BC0, c1 = BC1, c2 = BC2, c3 = BC3;
  const float nb = -1e35f;
  float b0, b1, b2, b3, p, q, r;
  asm("v_mul_f32 %[b0], %[s0], %[fx]\n\t"
      "v_mul_f32 %[b1], %[s1], %[fx]\n\t"
      "v_mul_f32 %[b2], %[s2], %[fx]\n\t"
      "v_mul_f32 %[b3], %[s3], %[fx]\n\t"
      "v_fma_f32 %[p], |%[gy]|, %[c0], -%[b0] clamp\n\t"
      "v_fma_f32 %[q], |%[gy]|, %[c1], -%[b1] clamp\n\t"
      "v_fma_f32 %[r], |%[gy]|, %[c2], -%[b2] clamp\n\t"
      "v_fmac_f32 %[a0], %[mg], %[p]\n\t"
      "v_fma_f32 %[p], |%[gy]|, %[c3], -%[b3] clamp\n\t"
      "v_fmac_f32 %[a1], %[mg], %[q]\n\t"
      "v_fma_f32 %[q], |%[gy]|, -%[c0], -%[b0] clamp\n\t"
      "v_fmac_f32 %[a2], %[mg], %[r]\n\t"
      "v_fma_f32 %[r], |%[gy]|, -%[c1], -%[b1] clamp\n\t"
      "v_fmac_f32 %[a3], %[mg], %[p]\n\t"
      "v_fma_f32 %[p], |%[gy]|, -%[c2], -%[b2] clamp\n\t"
      "v_fmac_f32 %[a8], %[mg], %[q]\n\t"
      "v_fma_f32 %[q], |%[gy]|, -%[c3], -%[b3] clamp\n\t"
      "v_fmac_f32 %[a7], %[mg], %[r]\n\t"
      "v_mul_f32 %[r], %[nb], %[fx] clamp\n\t"
      "v_fmac_f32 %[a6], %[mg], %[p]\n\t"
      "v_fmac_f32 %[a5], %[mg], %[q]\n\t"
      "v_fmac_f32 %[a4], %[mg], %[r]"
      : [b0] "=&v"(b0), [b1] "=&v"(b1), [b2] "=&v"(b2), [b3] "=&v"(b3),
        [p] "=&v"(p), [q] "=&v"(q), [r] "=&v"(r),
        [a0] "+v"(acc[0]), [a1] "+v"(acc[1]), [a2] "+v"(acc[2]), [a3] "+v"(acc[3]),
        [a4] "+v"(acc[4]), [a5] "+v"(acc[5]), [a6] "+v"(acc[6]), [a7] "+v"(acc[7]),
        [a8] "+v"(acc[8])
      : [fx] "v"(fx), [gy] "v"(gy), [mg] "v"(mag),
        [s0] "s"(s0), [s1] "s"(s1), [s2] "s"(s2), [s3] "s"(s3),
        [c0] "s"(c0), [c1] "s"(c1), [c2] "s"(c2), [c3] "s"(c3), [nb] "s"(nb));
  acc[9] += mag;
}

// gradient + binning for one output row (8 px) from lap rows A,B,C
__device__ __forceinline__ void out_row8(const float A[10], const float B[10], const float C[10],
                                         float acc[10]) {
  float cs[10], dd[10];
#pragma unroll
  for (int j = 0; j < 10; ++j) {
    cs[j] = A[j] + fmaf(2.f, B[j], C[j]);
    dd[j] = C[j] - A[j];
  }
#pragma unroll
  for (int c = 0; c < 8; ++c) {
    float gx = cs[c + 2] - cs[c];
    float gy = fmaf(2.f, dd[c + 1], dd[c] + dd[c + 2]);
    float mag = __builtin_amdgcn_sqrtf(fmaf(gx, gx, fmaf(gy, gy, 1e-8f)));
    unsigned sg = __float_as_uint(gy) & 0x80000000u;
    float fx = __uint_as_float(__float_as_uint(gx) ^ sg);  // sign(gy)*gx
    bin9(fx, gy, mag, acc);
  }
}

__global__ __launch_bounds__(256) void phog_hist_kernel(const float* __restrict__ x,
                                                        float* __restrict__ hist2) {
  const int tc = blockIdx.x;   // cell col 0..3
  const int bc = blockIdx.y;   // 0..511
  const int tid = threadIdx.x;
  const int tcol = tid & 7;    // 8 threads x 8 px = 64 cols (one cell wide)
  const int trow = tid >> 3;   // 32 threads x 8 px = 256 rows (whole column)

  const float* xim = x + (size_t)bc * (H_IMG * W_IMG);

  const int gr0 = 8 * trow;            // first output row
  const int gc0 = tc * 64 + 8 * tcol;  // first output col

  // col handling: window cols gc0-2..gc0+9 as 6 float2; edge clamp + mask
  const int o0 = (gc0 - 2 < 0) ? 0 : (gc0 - 2);
  const int o5 = (gc0 + 8 > 254) ? 254 : (gc0 + 8);
  const float mlo = (gc0 - 2 >= 0) ? 1.f : 0.f;     // x cols gc0-2,gc0-1
  const float mhi = (gc0 + 9 <= 255) ? 1.f : 0.f;   // x cols gc0+8,gc0+9
  const float wm0 = (gc0 >= 1) ? 1.f : 0.f;         // lap col gc0-1
  const float wm9 = (gc0 + 8 <= 255) ? 1.f : 0.f;   // lap col gc0+8

  const bool vlo = trow > 0;    // x rows gr0-2,gr0-1
  const bool vhi = trow < 31;   // x rows gr0+8,gr0+9
  const float rmf = vlo ? 1.f : 0.f;  // lap row gr0-1
  const float rml = vhi ? 1.f : 0.f;  // lap row gr0+8

  float acc[10];
#pragma unroll
  for (int k = 0; k < 10; ++k) acc[k] = 0.f;

  float xa[12], xb[12], xc[12];      // rolling x rows
  float La[10], Lb[10], Lc[10];      // rolling lap rows

  // x rows i=0..11 at global row gr0-2+i; lap rows j=0..9 at gr0-1+j
  load_xrow12(xim, gr0 - 2, vlo, o0, o5, gc0, mlo, mhi, xa);
  load_xrow12(xim, gr0 - 1, vlo, o0, o5, gc0, mlo, mhi, xb);
  load_xrow12(xim, gr0 + 0, true, o0, o5, gc0, mlo, mhi, xc);
  lap_row10_rm(La, xa, xb, xc, wm0, wm9, rmf);   // lap 0 (edge)
  load_xrow12(xim, gr0 + 1, true, o0, o5, gc0, mlo, mhi, xa);
  lap_row10(Lb, xb, xc, xa, wm0, wm9);           // lap 1
  load_xrow12(xim, gr0 + 2, true, o0, o5, gc0, mlo, mhi, xb);
  lap_row10(Lc, xc, xa, xb, wm0, wm9);           // lap 2
  out_row8(La, Lb, Lc, acc);                     // out 0
  load_xrow12(xim, gr0 + 3, true, o0, o5, gc0, mlo, mhi, xc);
  lap_row10(La, xa, xb, xc, wm0, wm9);           // lap 3
  out_row8(Lb, Lc, La, acc);                     // out 1
  load_xrow12(xim, gr0 + 4, true, o0, o5, gc0, mlo, mhi, xa);
  lap_row10(Lb, xb, xc, xa, wm0, wm9);           // lap 4
  out_row8(Lc, La, Lb, acc);                     // out 2
  load_xrow12(xim, gr0 + 5, true, o0, o5, gc0, mlo, mhi, xb);
  lap_row10(Lc, xc, xa, xb, wm0, wm9);           // lap 5
  out_row8(La, Lb, Lc, acc);                     // out 3
  load_xrow12(xim, gr0 + 6, true, o0, o5, gc0, mlo, mhi, xc);
  lap_row10(La, xa, xb, xc, wm0, wm9);           // lap 6
  out_row8(Lb, Lc, La, acc);                     // out 4
  load_xrow12(xim, gr0 + 7, true, o0, o5, gc0, mlo, mhi, xa);
  lap_row10(Lb, xb, xc, xa, wm0, wm9);           // lap 7
  out_row8(Lc, La, Lb, acc);                     // out 5
  load_xrow12(xim, gr0 + 8, vhi, o0, o5, gc0, mlo, mhi, xb);
  lap_row10(Lc, xc, xa, xb, wm0, wm9);           // lap 8
  out_row8(La, Lb, Lc, acc);                     // out 6
  load_xrow12(xim, gr0 + 9, vhi, o0, o5, gc0, mlo, mhi, xc);
  lap_row10_rm(La, xa, xb, xc, wm0, wm9, rml);   // lap 9 (edge)
  out_row8(Lb, Lc, La, acc);                     // out 7

  // wave = exactly one 64x64 cell -> full 64-lane butterfly, no LDS/barriers
#pragma unroll
  for (int k = 0; k < 10; ++k) {
    float v = acc[k];
#pragma unroll
    for (int off = 32; off > 0; off >>= 1) v += __shfl_xor(v, off);
    acc[k] = v;
  }
  const int lane = tid & 63;
  const int w = tid >> 6;  // wave id == cell row
  if (lane == 0) {
    float* dst = &hist2[((bc * 16) + (w * 4 + tc)) * 9];
    dst[0] = (acc[9] - acc[0]) + acc[8];
#pragma unroll
    for (int k = 1; k < 9; ++k) dst[k] = acc[k - 1] - acc[k];
  }
}

__global__ __launch_bounds__(256) void phog_norm_kernel(const float* __restrict__ hist2,
                                                        float* __restrict__ out) {
  int t = blockIdx.x * 256 + threadIdx.x;
  if (t >= 32 * 336) return;
  int b = t / 336;
  int r = t - b * 336;

  float h[9];
  if (r < 16) {
    const float* p = hist2 + (b * 16 + r) * 144;
#pragma unroll
    for (int k = 0; k < 9; ++k) {
      float s = 0.f;
#pragma unroll
      for (int cell = 0; cell < 16; ++cell) s += p[cell * 9 + k];
      h[k] = s;
    }
  } else if (r < 80) {
    int q = r - 16;
    int c = q >> 2;
    int cell = q & 3;
    int r1 = cell >> 1, c1 = cell & 1;
    const float* p = hist2 + (b * 16 + c) * 144;
    int i00 = ((2 * r1) * 4 + 2 * c1) * 9;
    int i01 = ((2 * r1) * 4 + 2 * c1 + 1) * 9;
    int i10 = ((2 * r1 + 1) * 4 + 2 * c1) * 9;
    int i11 = ((2 * r1 + 1) * 4 + 2 * c1 + 1) * 9;
#pragma unroll
    for (int k = 0; k < 9; ++k) h[k] = (p[i00 + k] + p[i01 + k]) + (p[i10 + k] + p[i11 + k]);
  } else {
    int q = r - 80;
    int c = q >> 4;
    int cell = q & 15;
    const float* p = hist2 + ((b * 16 + c) * 16 + cell) * 9;
#pragma unroll
    for (int k = 0; k < 9; ++k) h[k] = p[k];
  }

  float s = 0.f;
#pragma unroll
  for (int k = 0; k < 9; ++k) s += h[k];
  float inv = 1.f / (s + 1e-8f);
#pragma unroll
  for (int k = 0; k < 9; ++k) h[k] *= inv;
  float n2 = 0.f;
#pragma unroll
  for (int k = 0; k < 9; ++k) n2 = fmaf(h[k], h[k], n2);
  float nrm = sqrtf(n2);
  float inv2 = 1.f / fmaxf(nrm, 1e-12f);
#pragma unroll
  for (int k = 0; k < 9; ++k) out[t * 9 + k] = h[k] * inv2;
}

extern "C" void kernel_launch(void* const* d_in, const int* in_sizes, int n_in,
                              void* d_out, int out_size, void* d_ws, size_t ws_size,
                              hipStream_t stream) {
  const float* x = (const float*)d_in[0];
  float* out = (float*)d_out;
  float* hist2 = (float*)d_ws;  // 512*16*9 floats = 294912 B

  dim3 g1(4, 512);
  phog_hist_kernel<<<g1, 256, 0, stream>>>(x, hist2);

  int total = 32 * 336;
  phog_norm_kernel<<<(total + 255) / 256, 256, 0, stream>>>(hist2, out);
}